// Round 2
// baseline (165.873 us; speedup 1.0000x reference)
//
#include <hip/hip_runtime.h>

// Problem constants (STEP=3 -> INTERVAL=1, W_LEN=3, N_TOK=7)
#define BB 8
#define NN 1024
#define DD 1024
#define RR 256
#define MM (BB * NN)   // 8192 rows of P
#define NTOK 7

// ---------------- GEMM: P[m][c] = sum_k X[m][k] * W[c][k] ----------------
#define BM 64
#define BN 64
#define BK 16

__global__ __launch_bounds__(256) void gemm_xwT(const float* __restrict__ X,
                                                const float* __restrict__ Wt,
                                                float* __restrict__ P) {
  __shared__ __align__(16) float As[BK][BM + 4];  // k-major, row stride 68 floats (16B aligned)
  __shared__ __align__(16) float Bs[BK][BN + 4];
  const int tid = threadIdx.x;
  const int row0 = blockIdx.x * BM;
  const int col0 = blockIdx.y * BN;
  const int lr = tid >> 2;         // 0..63: tile row for staging
  const int lk = (tid & 3) << 2;   // 0,4,8,12: k offset for staging
  const int ty = tid >> 4;         // 0..15
  const int tx = tid & 15;         // 0..15

  float acc[4][4] = {};

  for (int k0 = 0; k0 < DD; k0 += BK) {
    float4 av = *reinterpret_cast<const float4*>(&X[(size_t)(row0 + lr) * DD + k0 + lk]);
    float4 bv = *reinterpret_cast<const float4*>(&Wt[(size_t)(col0 + lr) * DD + k0 + lk]);
    __syncthreads();  // previous iteration's LDS reads done
    As[lk + 0][lr] = av.x; As[lk + 1][lr] = av.y; As[lk + 2][lr] = av.z; As[lk + 3][lr] = av.w;
    Bs[lk + 0][lr] = bv.x; Bs[lk + 1][lr] = bv.y; Bs[lk + 2][lr] = bv.z; Bs[lk + 3][lr] = bv.w;
    __syncthreads();
#pragma unroll
    for (int k = 0; k < BK; ++k) {
      float4 a = *reinterpret_cast<const float4*>(&As[k][ty * 4]);
      float4 b = *reinterpret_cast<const float4*>(&Bs[k][tx * 4]);
      float ar[4] = {a.x, a.y, a.z, a.w};
      float br[4] = {b.x, b.y, b.z, b.w};
#pragma unroll
      for (int i = 0; i < 4; ++i)
#pragma unroll
        for (int j = 0; j < 4; ++j) acc[i][j] += ar[i] * br[j];
    }
  }

#pragma unroll
  for (int i = 0; i < 4; ++i) {
    const int row = row0 + ty * 4 + i;
    float4 v = make_float4(acc[i][0], acc[i][1], acc[i][2], acc[i][3]);
    *reinterpret_cast<float4*>(&P[(size_t)row * RR + col0 + tx * 4]) = v;
  }
}

// ---------------- Ppad[c] = sum_k pad[k] * W[c][k] ----------------
__global__ void pad_proj(const float* __restrict__ Wt, const float* __restrict__ pad,
                         float* __restrict__ Ppad) {
  const int c = blockIdx.x;
  const int lane = threadIdx.x;  // 64
  float s = 0.f;
  for (int k = lane; k < DD; k += 64) s += Wt[(size_t)c * DD + k] * pad[k];
#pragma unroll
  for (int off = 32; off; off >>= 1) s += __shfl_down(s, off);
  if (lane == 0) Ppad[c] = s;
}

// ---------------- Assembly ----------------
// out[b][j][t][c], j==0 row is zeros; else i=j-1:
//   t=0          : (reg[c] + pos[0][c]) * mask[b][0]
//   t=1..3 (w)   : (Q[w-1] + pos[t][c]) * mask[b][t]
//   t=4..6 (w)   : (Q[t-4] - Q[1] + pos[t][c]) * mask[b][t]
// with Q[w] = (i+w==0 ? Ppad : P[b*NN + i+w-1])
__global__ __launch_bounds__(256) void assemble(const float* __restrict__ P,
                                                const float* __restrict__ Ppad,
                                                const float* __restrict__ mask,
                                                const float* __restrict__ pos,
                                                const float* __restrict__ regtok,
                                                float* __restrict__ out) {
  const size_t gid = (size_t)blockIdx.x * blockDim.x + threadIdx.x;  // B*N*64 threads
  const int c = (int)(gid & 63) * 4;
  const int j = (int)((gid >> 6) & (NN - 1));
  const int b = (int)(gid >> 16);  // gid / (NN*64)

  float* outp = out + (((size_t)b * NN + j) * NTOK) * RR + c;

  if (j == 0) {
    float4 z = make_float4(0.f, 0.f, 0.f, 0.f);
#pragma unroll
    for (int t = 0; t < NTOK; ++t)
      *reinterpret_cast<float4*>(outp + (size_t)t * RR) = z;
    return;
  }

  const int i = j - 1;
  float4 q[3];
#pragma unroll
  for (int w = 0; w < 3; ++w) {
    const int src = i + w - 1;
    q[w] = (src < 0)
               ? *reinterpret_cast<const float4*>(Ppad + c)
               : *reinterpret_cast<const float4*>(P + ((size_t)b * NN + src) * RR + c);
  }
  const float4 rg = *reinterpret_cast<const float4*>(regtok + c);

  float mk[NTOK];
#pragma unroll
  for (int t = 0; t < NTOK; ++t) mk[t] = mask[b * NTOK + t];

#pragma unroll
  for (int t = 0; t < NTOK; ++t) {
    const float4 ps = *reinterpret_cast<const float4*>(pos + (size_t)t * RR + c);
    float4 v;
    if (t == 0) {
      v = rg;
    } else if (t <= 3) {
      v = q[t - 1];
    } else {
      const int w = t - 4;
      v = make_float4(q[w].x - q[1].x, q[w].y - q[1].y, q[w].z - q[1].z, q[w].w - q[1].w);
    }
    v.x = (v.x + ps.x) * mk[t];
    v.y = (v.y + ps.y) * mk[t];
    v.z = (v.z + ps.z) * mk[t];
    v.w = (v.w + ps.w) * mk[t];
    *reinterpret_cast<float4*>(outp + (size_t)t * RR) = v;
  }
}

extern "C" void kernel_launch(void* const* d_in, const int* in_sizes, int n_in,
                              void* d_out, int out_size, void* d_ws, size_t ws_size,
                              hipStream_t stream) {
  const float* x      = (const float*)d_in[0];  // (8,1024,1024)
  const float* mask   = (const float*)d_in[1];  // (8,7,1)
  const float* W      = (const float*)d_in[2];  // (256,1024)
  const float* pos    = (const float*)d_in[3];  // (1,7,256)
  const float* regtok = (const float*)d_in[4];  // (1,1,256)
  const float* pad    = (const float*)d_in[5];  // (1,1,1024)
  float* out = (float*)d_out;

  float* P    = (float*)d_ws;              // 8192*256 f32 = 8 MiB
  float* Ppad = P + (size_t)MM * RR;       // 256 f32

  gemm_xwT<<<dim3(MM / BM, RR / BN), 256, 0, stream>>>(x, W, P);
  pad_proj<<<RR, 64, 0, stream>>>(W, pad, Ppad);
  assemble<<<(BB * NN * 64) / 256, 256, 0, stream>>>(P, Ppad, mask, pos, regtok, out);
}

// Round 3
// 138.359 us; speedup vs baseline: 1.1989x; 1.1989x over previous
//
#include <hip/hip_runtime.h>

// Problem constants (STEP=3 -> INTERVAL=1, W_LEN=3, N_TOK=7)
#define BB 8
#define NN 1024
#define DD 1024
#define RR 256
#define MM (BB * NN)   // 8192 rows of P
#define NTOK 7

typedef __bf16 bf16x8 __attribute__((ext_vector_type(8)));
typedef float f32x4 __attribute__((ext_vector_type(4)));

// ---------------- W f32 -> bf16 (256x1024, L2-resident afterwards) ----------------
__global__ __launch_bounds__(256) void wcvt(const float* __restrict__ W, __bf16* __restrict__ Wb) {
  const int i = (blockIdx.x * 256 + threadIdx.x) * 4;  // 256 blocks x 256 thr x 4 = 262144
  float4 v = *reinterpret_cast<const float4*>(W + i);
  union { __bf16 b[4]; ushort4 u; } p;
  p.b[0] = (__bf16)v.x; p.b[1] = (__bf16)v.y; p.b[2] = (__bf16)v.z; p.b[3] = (__bf16)v.w;
  *reinterpret_cast<ushort4*>(Wb + i) = p.u;
}

// ---------------- MFMA GEMM: P[m][c] = sum_k X[m][k] * W[c][k] ----------------
// grid = MM/32 blocks, 256 threads = 4 waves. Wave w: rows [bx*32, bx*32+32), cols [w*64, w*64+64).
// No LDS, no barriers: A from global f32 (+cvt), B from global bf16 (L2-hot). 2-deep pipeline.
__device__ __forceinline__ bf16x8 cvt8(const float4& lo, const float4& hi) {
  bf16x8 r;
  r[0] = (__bf16)lo.x; r[1] = (__bf16)lo.y; r[2] = (__bf16)lo.z; r[3] = (__bf16)lo.w;
  r[4] = (__bf16)hi.x; r[5] = (__bf16)hi.y; r[6] = (__bf16)hi.z; r[7] = (__bf16)hi.w;
  return r;
}

__global__ __launch_bounds__(256) void gemm_mfma(const float* __restrict__ X,
                                                 const __bf16* __restrict__ Wb,
                                                 float* __restrict__ P) {
  const int tid = threadIdx.x;
  const int wave = tid >> 6;
  const int lane = tid & 63;
  const int m0 = blockIdx.x * 32;
  const int c0 = wave * 64;
  const int lr = lane & 15;   // row/col within fragment
  const int lg = lane >> 4;   // k-group (8 elems each)

  const float*  xb0 = X  + (size_t)(m0 + lr) * DD + lg * 8;        // A frag 0 (rows m0..m0+15)
  const float*  xb1 = xb0 + (size_t)16 * DD;                        // A frag 1 (rows m0+16..)
  const __bf16* wb  = Wb + (size_t)(c0 + lr) * DD + lg * 8;        // B frag base

  f32x4 acc[2][4] = {};

  float4 a0[2][2], a1[2][2];
  bf16x8 b0[4], b1[4];

#define LD_A(dst, kk) do {                                          \
    dst[0][0] = *reinterpret_cast<const float4*>(xb0 + (kk));       \
    dst[0][1] = *reinterpret_cast<const float4*>(xb0 + (kk) + 4);   \
    dst[1][0] = *reinterpret_cast<const float4*>(xb1 + (kk));       \
    dst[1][1] = *reinterpret_cast<const float4*>(xb1 + (kk) + 4);   \
  } while (0)
#define LD_B(dst, kk) do {                                          \
    dst[0] = *reinterpret_cast<const bf16x8*>(wb + (kk));           \
    dst[1] = *reinterpret_cast<const bf16x8*>(wb + 16 * DD + (kk)); \
    dst[2] = *reinterpret_cast<const bf16x8*>(wb + 32 * DD + (kk)); \
    dst[3] = *reinterpret_cast<const bf16x8*>(wb + 48 * DD + (kk)); \
  } while (0)
#define MFMA_STEP(aS, bS) do {                                      \
    bf16x8 af0 = cvt8(aS[0][0], aS[0][1]);                          \
    bf16x8 af1 = cvt8(aS[1][0], aS[1][1]);                          \
    acc[0][0] = __builtin_amdgcn_mfma_f32_16x16x32_bf16(af0, bS[0], acc[0][0], 0, 0, 0); \
    acc[1][0] = __builtin_amdgcn_mfma_f32_16x16x32_bf16(af1, bS[0], acc[1][0], 0, 0, 0); \
    acc[0][1] = __builtin_amdgcn_mfma_f32_16x16x32_bf16(af0, bS[1], acc[0][1], 0, 0, 0); \
    acc[1][1] = __builtin_amdgcn_mfma_f32_16x16x32_bf16(af1, bS[1], acc[1][1], 0, 0, 0); \
    acc[0][2] = __builtin_amdgcn_mfma_f32_16x16x32_bf16(af0, bS[2], acc[0][2], 0, 0, 0); \
    acc[1][2] = __builtin_amdgcn_mfma_f32_16x16x32_bf16(af1, bS[2], acc[1][2], 0, 0, 0); \
    acc[0][3] = __builtin_amdgcn_mfma_f32_16x16x32_bf16(af0, bS[3], acc[0][3], 0, 0, 0); \
    acc[1][3] = __builtin_amdgcn_mfma_f32_16x16x32_bf16(af1, bS[3], acc[1][3], 0, 0, 0); \
  } while (0)

  LD_A(a0, 0); LD_B(b0, 0);
  for (int k0 = 0; k0 < DD - 64; k0 += 64) {
    LD_A(a1, k0 + 32); LD_B(b1, k0 + 32);
    MFMA_STEP(a0, b0);
    LD_A(a0, k0 + 64); LD_B(b0, k0 + 64);
    MFMA_STEP(a1, b1);
  }
  LD_A(a1, DD - 32); LD_B(b1, DD - 32);
  MFMA_STEP(a0, b0);
  MFMA_STEP(a1, b1);

#undef LD_A
#undef LD_B
#undef MFMA_STEP

  // C/D layout (verified m89/m91): col = lane&15, row = 4*(lane>>4) + reg
#pragma unroll
  for (int mi = 0; mi < 2; ++mi)
#pragma unroll
    for (int ni = 0; ni < 4; ++ni) {
      const int col = c0 + ni * 16 + lr;
#pragma unroll
      for (int r = 0; r < 4; ++r) {
        const int row = m0 + mi * 16 + lg * 4 + r;
        P[(size_t)row * RR + col] = acc[mi][ni][r];
      }
    }
}

// ---------------- Ppad[c] = sum_k pad[k] * W[c][k] (exact f32) ----------------
__global__ void pad_proj(const float* __restrict__ Wt, const float* __restrict__ pad,
                         float* __restrict__ Ppad) {
  const int c = blockIdx.x;
  const int lane = threadIdx.x;  // 64
  float s = 0.f;
  for (int k = lane; k < DD; k += 64) s += Wt[(size_t)c * DD + k] * pad[k];
#pragma unroll
  for (int off = 32; off; off >>= 1) s += __shfl_down(s, off);
  if (lane == 0) Ppad[c] = s;
}

// ---------------- Assembly ----------------
__global__ __launch_bounds__(256) void assemble(const float* __restrict__ P,
                                                const float* __restrict__ Ppad,
                                                const float* __restrict__ mask,
                                                const float* __restrict__ pos,
                                                const float* __restrict__ regtok,
                                                float* __restrict__ out) {
  const size_t gid = (size_t)blockIdx.x * blockDim.x + threadIdx.x;  // B*N*64 threads
  const int c = (int)(gid & 63) * 4;
  const int j = (int)((gid >> 6) & (NN - 1));
  const int b = (int)(gid >> 16);  // gid / (NN*64)

  float* outp = out + (((size_t)b * NN + j) * NTOK) * RR + c;

  if (j == 0) {
    float4 z = make_float4(0.f, 0.f, 0.f, 0.f);
#pragma unroll
    for (int t = 0; t < NTOK; ++t)
      *reinterpret_cast<float4*>(outp + (size_t)t * RR) = z;
    return;
  }

  const int i = j - 1;
  float4 q[3];
#pragma unroll
  for (int w = 0; w < 3; ++w) {
    const int src = i + w - 1;
    q[w] = (src < 0)
               ? *reinterpret_cast<const float4*>(Ppad + c)
               : *reinterpret_cast<const float4*>(P + ((size_t)b * NN + src) * RR + c);
  }
  const float4 rg = *reinterpret_cast<const float4*>(regtok + c);

  float mk[NTOK];
#pragma unroll
  for (int t = 0; t < NTOK; ++t) mk[t] = mask[b * NTOK + t];

#pragma unroll
  for (int t = 0; t < NTOK; ++t) {
    const float4 ps = *reinterpret_cast<const float4*>(pos + (size_t)t * RR + c);
    float4 v;
    if (t == 0) {
      v = rg;
    } else if (t <= 3) {
      v = q[t - 1];
    } else {
      const int w = t - 4;
      v = make_float4(q[w].x - q[1].x, q[w].y - q[1].y, q[w].z - q[1].z, q[w].w - q[1].w);
    }
    v.x = (v.x + ps.x) * mk[t];
    v.y = (v.y + ps.y) * mk[t];
    v.z = (v.z + ps.z) * mk[t];
    v.w = (v.w + ps.w) * mk[t];
    *reinterpret_cast<float4*>(outp + (size_t)t * RR) = v;
  }
}

extern "C" void kernel_launch(void* const* d_in, const int* in_sizes, int n_in,
                              void* d_out, int out_size, void* d_ws, size_t ws_size,
                              hipStream_t stream) {
  const float* x      = (const float*)d_in[0];  // (8,1024,1024)
  const float* mask   = (const float*)d_in[1];  // (8,7,1)
  const float* W      = (const float*)d_in[2];  // (256,1024)
  const float* pos    = (const float*)d_in[3];  // (1,7,256)
  const float* regtok = (const float*)d_in[4];  // (1,1,256)
  const float* pad    = (const float*)d_in[5];  // (1,1,1024)
  float* out = (float*)d_out;

  // ws layout: P (8 MiB) | Wb (512 KiB) | Ppad (1 KiB)
  float*   P    = (float*)d_ws;
  __bf16*  Wb   = (__bf16*)((char*)d_ws + (size_t)MM * RR * 4);
  float*   Ppad = (float*)((char*)d_ws + (size_t)MM * RR * 4 + (size_t)RR * DD * 2);

  wcvt<<<RR * DD / (256 * 4), 256, 0, stream>>>(W, Wb);
  gemm_mfma<<<MM / 32, 256, 0, stream>>>(x, Wb, P);
  pad_proj<<<RR, 64, 0, stream>>>(W, pad, Ppad);
  assemble<<<(BB * NN * 64) / 256, 256, 0, stream>>>(P, Ppad, mask, pos, regtok, out);
}